// Round 7
// baseline (767.537 us; speedup 1.0000x reference)
//
#include <hip/hip_runtime.h>
#include <cstdint>
#include <cstddef>

typedef unsigned short u16;
typedef unsigned int   u32;

typedef short bf16x8 __attribute__((ext_vector_type(8)));
typedef float f32x4  __attribute__((ext_vector_type(4)));

// ---------------- helpers ----------------
__device__ __forceinline__ u16 f2bf(float f) {   // RNE f32 -> bf16
  u32 u = __float_as_uint(f);
  u += 0x7fffu + ((u >> 16) & 1u);
  return (u16)(u >> 16);
}
__device__ __forceinline__ float bflo(u32 w) { return __uint_as_float((w & 0xffffu) << 16); }
__device__ __forceinline__ float bfhi(u32 w) { return __uint_as_float(w & 0xffff0000u); }

#define GLB_AS(p) ((const __attribute__((address_space(1))) void*)(p))
#define LDS_AS(p) ((__attribute__((address_space(3))) void*)(p))

// ---------------- fused f32 -> bf16 convert: inputs + Wi + Wo ----------------
// R13: grid-stride (4096 blocks), ~8.5 quads/thread -- amortizes block churn
// (17408 one-shot blocks ran well under copy ceiling). Same per-quad logic.
__global__ __launch_bounds__(256)
void conv3_f32_bf16(const float* __restrict__ in, u16* __restrict__ a,
                    const float* __restrict__ wi, u16* __restrict__ wib,
                    const float* __restrict__ wo, u16* __restrict__ wob)
{
  const long total = 4456448L;   // 4194304 + 131072 + 131072 quads
  for (long i = (long)blockIdx.x * 256 + threadIdx.x; i < total;
       i += (long)gridDim.x * 256) {
    long j = i; const float* src; u16* dst;
    if (j < 4194304L) { src = in; dst = a; }
    else if (j < 4325376L) { j -= 4194304L; src = wi; dst = wib; }
    else { j -= 4325376L; src = wo; dst = wob; }
    float4 v = ((const float4*)src)[j];
    u32 lo = (u32)f2bf(v.x) | ((u32)f2bf(v.y) << 16);
    u32 hi = (u32)f2bf(v.z) | ((u32)f2bf(v.w) << 16);
    ((uint2*)dst)[j] = make_uint2(lo, hi);
  }
}

// ---------------- bf16 GEMM, 256x128 tile, BK=32, 512 thr, XCD-local --------
// Validated R3/R9 geometry: 256x128, 3-buffer counted vmcnt, 2 blocks/CU,
// 49us each. (R11's 256x256 regressed: 1 block/CU + barrier lockstep.)
template<int N, int K, int LOGNB, int OUT_BF16, int RELU>
__global__ __launch_bounds__(512, 4)
void gemm_w2(const u16* __restrict__ A, const u16* __restrict__ Bw,
             const float* __restrict__ bias, void* __restrict__ Cout)
{
  __shared__ __align__(16) u16 As[3][256 * 32];   // 3 x 16 KB
  __shared__ __align__(16) u16 Bs[3][128 * 32];   // 3 x  8 KB  (72 KB total)

  const int tid  = threadIdx.x;
  const int lane = tid & 63;
  const int wave = tid >> 6;
  const int bid  = blockIdx.x;
  const int xcd  = bid & 7;
  const int s    = bid >> 3;
  const int m0 = (xcd * 16 + (s >> LOGNB)) * 256;
  const int n0 = (s & ((1 << LOGNB) - 1)) * 128;
  const int wm = (wave & 3) * 64;
  const int wn = (wave >> 2) * 64;

  f32x4 acc[4][4];
#pragma unroll
  for (int i = 0; i < 4; ++i)
#pragma unroll
    for (int j = 0; j < 4; ++j) acc[i][j] = f32x4{0.f, 0.f, 0.f, 0.f};

  const u16* Ap[2]; const u16* Bp; int ldsA[2]; int ldsB;
#pragma unroll
  for (int i = 0; i < 2; ++i) {
    int g = i * 512 + tid;
    int r = g >> 2;
    int koff = ((g & 3) ^ ((r >> 1) & 3)) << 3;
    Ap[i]   = A + (size_t)(m0 + r) * K + koff;
    ldsA[i] = (i * 512 + wave * 64) * 8;        // wave-uniform base (u16)
  }
  {
    int g = tid;
    int r = g >> 2;
    int koff = ((g & 3) ^ ((r >> 1) & 3)) << 3;
    Bp   = Bw + (size_t)(n0 + r) * K + koff;
    ldsB = (wave * 64) * 8;
  }

  const int fm = lane & 15;
  const int q  = lane >> 4;
  int aoff[4], boff[4];
#pragma unroll
  for (int i = 0; i < 4; ++i) {
    int m = wm + i * 16 + fm;
    aoff[i] = (m * 4 + (q ^ ((m >> 1) & 3))) * 8;
    int n = wn + i * 16 + fm;
    boff[i] = (n * 4 + (q ^ ((n >> 1) & 3))) * 8;
  }

  auto stage = [&](int buf, int kt) {
    __builtin_amdgcn_global_load_lds(GLB_AS(Ap[0] + kt), LDS_AS(&As[buf][ldsA[0]]), 16, 0, 0);
    __builtin_amdgcn_global_load_lds(GLB_AS(Ap[1] + kt), LDS_AS(&As[buf][ldsA[1]]), 16, 0, 0);
    __builtin_amdgcn_global_load_lds(GLB_AS(Bp    + kt), LDS_AS(&Bs[buf][ldsB]),    16, 0, 0);
  };
  auto compute = [&](int buf) {
    bf16x8 af[4], bfr[4];
#pragma unroll
    for (int i = 0; i < 4; ++i) { af[i]  = *(const bf16x8*)&As[buf][aoff[i]];
                                  bfr[i] = *(const bf16x8*)&Bs[buf][boff[i]]; }
#pragma unroll
    for (int mi = 0; mi < 4; ++mi)
#pragma unroll
      for (int ni = 0; ni < 4; ++ni)
        acc[mi][ni] = __builtin_amdgcn_mfma_f32_16x16x32_bf16(af[mi], bfr[ni],
                                                              acc[mi][ni], 0, 0, 0);
  };

  constexpr int NT = K / 32;
  stage(0, 0);
  stage(1, 32);                       // depth-2 prefetch in flight
#pragma unroll
  for (int t = 0; t < NT - 1; ++t) {
    asm volatile("s_waitcnt vmcnt(3)" ::: "memory");
    __builtin_amdgcn_s_barrier();     // all waves' tile-t DMA landed; t-1 reads done
    if (t + 2 < NT) stage((t + 2) % 3, (t + 2) * 32);
    compute(t % 3);
  }
  asm volatile("s_waitcnt vmcnt(0)" ::: "memory");
  __builtin_amdgcn_s_barrier();
  compute((NT - 1) % 3);

  const int colL = lane & 15;
  const int rowQ = (lane >> 4) * 4;
#pragma unroll
  for (int mi = 0; mi < 4; ++mi) {
#pragma unroll
    for (int ni = 0; ni < 4; ++ni) {
      int col  = n0 + wn + ni * 16 + colL;
      int rowb = m0 + wm + mi * 16 + rowQ;
      float bv = bias[col];
#pragma unroll
      for (int r = 0; r < 4; ++r) {
        float v = acc[mi][ni][r] + bv;
        if (RELU) v = fmaxf(v, 0.f);
        size_t idx = (size_t)(rowb + r) * N + col;
        if (OUT_BF16) ((u16*)Cout)[idx] = f2bf(v);
        else          ((float*)Cout)[idx] = v;
      }
    }
  }
}

// ---------------- single-pass scan with decoupled lookback ----------------
// R13: replaces scan_chunk_end + scan_mid + scan_out2. Block (c,b), 256 thr,
// 2 ch/thread. Reads u ONCE into regs (32 x uint2 = 64 VGPR), computes local
// aggregate, publishes it (syncthreads drains stores; threadfence + agent-
// scope release flag), walks predecessors' aggregates (Lambda-weighted sum,
// flags checked 4-at-a-time), then emits output from regs with the carry.
// Safety: 1024 blocks x 4 waves = 4096 waves vs 8192 capacity -> all blocks
// co-resident (no LDS, ~130 VGPR); x-major dispatch launches predecessors
// first. Flags are memset to 0 each launch. Carry association differs from
// the sequential reference only in fp32 rounding (<< bf16 threshold).
__global__ __launch_bounds__(256)
void scan_fused(const u16* __restrict__ u, const float* __restrict__ plog,
                float4* __restrict__ e, u32* __restrict__ flags,
                u16* __restrict__ xr)
{
  const int t = threadIdx.x;          // channel pair 2t, 2t+1
  const int c = blockIdx.x;           // chunk 0..127 (32 steps each)
  const int b = blockIdx.y;           // batch 0..7

  float2 vl = ((const float2*)plog)[t];
  float2 tl = ((const float2*)plog)[256 + t];
  float2 gl = ((const float2*)plog)[512 + t];
  float v0 = expf(vl.x), v1 = expf(vl.y);
  float t0 = expf(tl.x), t1 = expf(tl.y);
  float g0 = expf(gl.x), g1 = expf(gl.y);
  float m0 = expf(-v0), m1 = expf(-v1);
  float lr0 = m0 * cosf(t0), li0 = m0 * sinf(t0);
  float lr1 = m1 * cosf(t1), li1 = m1 * sinf(t1);

  // ---- 1) load chunk into regs + local scan (h = 0) ----
  const uint2* up = (const uint2*)u;
  size_t uidx = (size_t)(b * 4096 + c * 32) * 256 + t;
  uint2 ur[32];
#pragma unroll
  for (int s = 0; s < 32; ++s) { ur[s] = up[uidx]; uidx += 256; }

  float h0r = 0.f, h0i = 0.f, h1r = 0.f, h1i = 0.f;
#pragma unroll
  for (int s = 0; s < 32; ++s) {
    float u0r = bflo(ur[s].x), u0i = bfhi(ur[s].x);
    float u1r = bflo(ur[s].y), u1i = bfhi(ur[s].y);
    float n0r = fmaf(lr0, h0r, fmaf(-li0, h0i, u0r));
    float n0i = fmaf(lr0, h0i, fmaf( li0, h0r, u0i));
    float n1r = fmaf(lr1, h1r, fmaf(-li1, h1i, u1r));
    float n1i = fmaf(lr1, h1i, fmaf( li1, h1r, u1i));
    h0r = n0r; h0i = n0i; h1r = n1r; h1i = n1i;
  }

  // ---- 2) publish aggregate ----
  const int fbase = b * 128;
  e[(size_t)(fbase + c) * 256 + t] = make_float4(h0r, h0i, h1r, h1i);
  __syncthreads();                        // all block stores drained to L2
  if (t == 0) {
    __threadfence();                      // device-scope: L2 writeback
    __hip_atomic_store(&flags[fbase + c], 1u, __ATOMIC_RELEASE,
                       __HIP_MEMORY_SCOPE_AGENT);
  }

  // ---- 3) lookback: carry = sum_{i<c} Lambda^(c-1-i) * E[i] ----
  float cr0 = 0.f, ci0 = 0.f, cr1 = 0.f, ci1 = 0.f;
  if (c > 0) {
    // Lambda = lambda^32 per channel; powers 2..4 by complex squaring
    float Lm0 = expf(-32.f * v0), Lm1 = expf(-32.f * v1);
    float La0 = 32.f * t0,        La1 = 32.f * t1;
    float P1r0 = Lm0 * cosf(La0), P1i0 = Lm0 * sinf(La0);
    float P1r1 = Lm1 * cosf(La1), P1i1 = Lm1 * sinf(La1);
    float P2r0 = P1r0*P1r0 - P1i0*P1i0, P2i0 = 2.f*P1r0*P1i0;
    float P2r1 = P1r1*P1r1 - P1i1*P1i1, P2i1 = 2.f*P1r1*P1i1;
    float P3r0 = P2r0*P1r0 - P2i0*P1i0, P3i0 = P2r0*P1i0 + P2i0*P1r0;
    float P3r1 = P2r1*P1r1 - P2i1*P1i1, P3i1 = P2r1*P1i1 + P2i1*P1r1;
    float P4r0 = P2r0*P2r0 - P2i0*P2i0, P4i0 = 2.f*P2r0*P2i0;
    float P4r1 = P2r1*P2r1 - P2i1*P2i1, P4i1 = 2.f*P2r1*P2i1;

    float Wr0 = 1.f, Wi0 = 0.f, Wr1 = 1.f, Wi1 = 0.f;
    int i = c - 1;
    // singles until i is 4-aligned-top (i & 3 == 3) or exhausted
    while (i >= 0 && (i & 3) != 3) {
      if (t == 0)
        while (__hip_atomic_load(&flags[fbase + i], __ATOMIC_ACQUIRE,
                                 __HIP_MEMORY_SCOPE_AGENT) == 0u) {}
      __syncthreads();
      float4 ec = e[(size_t)(fbase + i) * 256 + t];
      cr0 = fmaf(Wr0, ec.x, fmaf(-Wi0, ec.y, cr0));
      ci0 = fmaf(Wr0, ec.y, fmaf( Wi0, ec.x, ci0));
      cr1 = fmaf(Wr1, ec.z, fmaf(-Wi1, ec.w, cr1));
      ci1 = fmaf(Wr1, ec.w, fmaf( Wi1, ec.z, ci1));
      float nr0 = Wr0*P1r0 - Wi0*P1i0, ni0 = Wr0*P1i0 + Wi0*P1r0;
      float nr1 = Wr1*P1r1 - Wi1*P1i1, ni1 = Wr1*P1i1 + Wi1*P1r1;
      Wr0 = nr0; Wi0 = ni0; Wr1 = nr1; Wi1 = ni1;
      --i;
    }
    // batches of 4: [j, j+3], j = i-3, i & 3 == 3
    while (i >= 3) {
      int j = i - 3;
      if (t == 0) {
        for (;;) {
          u32 f0 = __hip_atomic_load(&flags[fbase + j],     __ATOMIC_ACQUIRE, __HIP_MEMORY_SCOPE_AGENT);
          u32 f1 = __hip_atomic_load(&flags[fbase + j + 1], __ATOMIC_ACQUIRE, __HIP_MEMORY_SCOPE_AGENT);
          u32 f2 = __hip_atomic_load(&flags[fbase + j + 2], __ATOMIC_ACQUIRE, __HIP_MEMORY_SCOPE_AGENT);
          u32 f3 = __hip_atomic_load(&flags[fbase + j + 3], __ATOMIC_ACQUIRE, __HIP_MEMORY_SCOPE_AGENT);
          if (f0 & f1 & f2 & f3) break;
        }
      }
      __syncthreads();
      float4 e3 = e[(size_t)(fbase + i)     * 256 + t];
      float4 e2 = e[(size_t)(fbase + i - 1) * 256 + t];
      float4 e1 = e[(size_t)(fbase + i - 2) * 256 + t];
      float4 e0 = e[(size_t)(fbase + i - 3) * 256 + t];
      // acc = E[i] + P1*E[i-1] + P2*E[i-2] + P3*E[i-3]   (per channel)
      float a0r = e3.x, a0i = e3.y, a1r = e3.z, a1i = e3.w;
      a0r = fmaf(P1r0, e2.x, fmaf(-P1i0, e2.y, a0r));
      a0i = fmaf(P1r0, e2.y, fmaf( P1i0, e2.x, a0i));
      a1r = fmaf(P1r1, e2.z, fmaf(-P1i1, e2.w, a1r));
      a1i = fmaf(P1r1, e2.w, fmaf( P1i1, e2.z, a1i));
      a0r = fmaf(P2r0, e1.x, fmaf(-P2i0, e1.y, a0r));
      a0i = fmaf(P2r0, e1.y, fmaf( P2i0, e1.x, a0i));
      a1r = fmaf(P2r1, e1.z, fmaf(-P2i1, e1.w, a1r));
      a1i = fmaf(P2r1, e1.w, fmaf( P2i1, e1.z, a1i));
      a0r = fmaf(P3r0, e0.x, fmaf(-P3i0, e0.y, a0r));
      a0i = fmaf(P3r0, e0.y, fmaf( P3i0, e0.x, a0i));
      a1r = fmaf(P3r1, e0.z, fmaf(-P3i1, e0.w, a1r));
      a1i = fmaf(P3r1, e0.w, fmaf( P3i1, e0.z, a1i));
      // carry += W * acc ; W *= P4
      cr0 = fmaf(Wr0, a0r, fmaf(-Wi0, a0i, cr0));
      ci0 = fmaf(Wr0, a0i, fmaf( Wi0, a0r, ci0));
      cr1 = fmaf(Wr1, a1r, fmaf(-Wi1, a1i, cr1));
      ci1 = fmaf(Wr1, a1i, fmaf( Wi1, a1r, ci1));
      float nr0 = Wr0*P4r0 - Wi0*P4i0, ni0 = Wr0*P4i0 + Wi0*P4r0;
      float nr1 = Wr1*P4r1 - Wi1*P4i1, ni1 = Wr1*P4i1 + Wi1*P4r1;
      Wr0 = nr0; Wi0 = ni0; Wr1 = nr1; Wi1 = ni1;
      i -= 4;
    }
  }

  // ---- 4) output from regs with carry ----
  h0r = cr0; h0i = ci0; h1r = cr1; h1i = ci1;
  u32* xp = (u32*)xr;                 // 512 u32 per output row of 1024 u16
  size_t xidx = (size_t)(b * 4096 + c * 32) * 512 + t;
#pragma unroll
  for (int s = 0; s < 32; ++s) {
    float u0r = bflo(ur[s].x), u0i = bfhi(ur[s].x);
    float u1r = bflo(ur[s].y), u1i = bfhi(ur[s].y);
    float n0r = fmaf(lr0, h0r, fmaf(-li0, h0i, u0r));
    float n0i = fmaf(lr0, h0i, fmaf( li0, h0r, u0i));
    float n1r = fmaf(lr1, h1r, fmaf(-li1, h1i, u1r));
    float n1i = fmaf(lr1, h1i, fmaf( li1, h1r, u1i));
    h0r = n0r; h0i = n0i; h1r = n1r; h1i = n1i;
    xp[xidx]       = (u32)f2bf(g0 * h0r) | ((u32)f2bf(g1 * h1r) << 16);
    xp[xidx + 256] = (u32)f2bf(g0 * h0i) | ((u32)f2bf(g1 * h1i) << 16);
    xidx += 512;
  }
}

// ---------------- launch ----------------
extern "C" void kernel_launch(void* const* d_in, const int* in_sizes, int n_in,
                              void* d_out, int out_size, void* d_ws, size_t ws_size,
                              hipStream_t stream)
{
  (void)in_sizes; (void)n_in; (void)out_size; (void)ws_size;
  const float* inputs = (const float*)d_in[0];
  const float* Wi     = (const float*)d_in[1];
  const float* bi     = (const float*)d_in[2];
  const float* Wo     = (const float*)d_in[3];
  const float* bo     = (const float*)d_in[4];
  const float* plog   = (const float*)d_in[5];

  char* ws = (char*)d_ws;
  u16*    xrA   = (u16*)(ws);                        // A_bf then xr_bf (64 MB)
  u16*    u_bf  = (u16*)(ws + 67108864ull);          // 64 MB
  u16*    Wi_bf = (u16*)(ws + 134217728ull);         // 1 MB
  u16*    Wo_bf = (u16*)(ws + 135266304ull);         // 1 MB
  float4* e_b   = (float4*)(ws + 136314880ull);      // 4 MB (8 x 128 x 256 float4)
  u32*    flags = (u32*)(ws + 140509184ull);         // 4 KB (8 x 128 flags)

  // 0) zero lookback flags (4 KB; graph-capture-safe)
  hipMemsetAsync(flags, 0, 8 * 128 * sizeof(u32), stream);

  // 1) convert all three fp32 tensors to bf16 (grid-stride)
  conv3_f32_bf16<<<4096, 256, 0, stream>>>(inputs, xrA, Wi, Wi_bf, Wo, Wo_bf);

  // 2) u = X @ Wi^T + bi   (M=32768, N=1024, K=512), bf16 out
  gemm_w2<1024, 512, 3, 1, 0><<<1024, 512, 0, stream>>>(xrA, Wi_bf, bi, u_bf);

  // 3) single-pass chunked complex scan + gamma (decoupled lookback)
  scan_fused<<<dim3(128, 8), 256, 0, stream>>>(u_bf, plog, e_b, flags, xrA);

  // 4) out = relu(xr @ Wo^T + bo)  (M=32768, N=512, K=1024), fp32 out
  gemm_w2<512, 1024, 2, 0, 1><<<512, 512, 0, stream>>>(xrA, Wo_bf, bo, d_out);
}

// Round 10
// 274.407 us; speedup vs baseline: 2.7971x; 2.7971x over previous
//
#include <hip/hip_runtime.h>
#include <cstdint>
#include <cstddef>

typedef unsigned short u16;
typedef unsigned int   u32;

typedef short bf16x8 __attribute__((ext_vector_type(8)));
typedef float f32x4  __attribute__((ext_vector_type(4)));

// ---------------- helpers ----------------
__device__ __forceinline__ u16 f2bf(float f) {   // RNE f32 -> bf16
  u32 u = __float_as_uint(f);
  u += 0x7fffu + ((u >> 16) & 1u);
  return (u16)(u >> 16);
}
__device__ __forceinline__ float bflo(u32 w) { return __uint_as_float((w & 0xffffu) << 16); }
__device__ __forceinline__ float bfhi(u32 w) { return __uint_as_float(w & 0xffff0000u); }

#define GLB_AS(p) ((const __attribute__((address_space(1))) void*)(p))
#define LDS_AS(p) ((__attribute__((address_space(3))) void*)(p))

// ---------------- fused f32 -> bf16 convert: inputs + Wi + Wo ----------------
// quads: inputs 4194304, Wi 131072, Wo 131072 -> 17408 blocks x 256 exactly.
__global__ __launch_bounds__(256)
void conv3_f32_bf16(const float* __restrict__ in, u16* __restrict__ a,
                    const float* __restrict__ wi, u16* __restrict__ wib,
                    const float* __restrict__ wo, u16* __restrict__ wob)
{
  long i = (long)blockIdx.x * 256 + threadIdx.x;
  const float* src; u16* dst;
  if (i < 4194304L) { src = in; dst = a; }
  else if (i < 4325376L) { i -= 4194304L; src = wi; dst = wib; }
  else { i -= 4325376L; if (i >= 131072L) return; src = wo; dst = wob; }
  float4 v = ((const float4*)src)[i];
  u32 lo = (u32)f2bf(v.x) | ((u32)f2bf(v.y) << 16);
  u32 hi = (u32)f2bf(v.z) | ((u32)f2bf(v.w) << 16);
  ((uint2*)dst)[i] = make_uint2(lo, hi);
}

// ---------------- bf16 GEMM, 256x256 tile, BK=64, 8-PHASE schedule ----------
// R15/R16: port of the guide's verified 256^2 8-phase template (T3+T4+T5)
// onto the validated R2 granule-swizzle maps. C[m,n] = sum_k A[m,k]*W[n,k].
// 8 waves = 2M x 4N, per-wave 128x64 out (acc 8x4 f32x4). BK=64 as two
// 32-k slabs, each slab = validated BK=32 layout (4 granules/row, XOR
// swizzle, 0 bank conflicts). LDS 2 x (32KB A + 32KB B) = 128KB, 1 blk/CU.
// Per K-tile, 4 phases: {stage-issue || ds_read subtile -> barrier ->
// lgkmcnt(0) -> sched_barrier(0) -> setprio(1) -> 16 MFMA -> setprio(0) ->
// barrier}. Quadrant (mh,nh): A-halves read P0/P2, B-halves P0/P1 (live
// P0-P3). Counted vmcnt(4) ONCE per K-tile at P0 (in-order retirement =>
// all of tile t landed), never 0 in-loop. Tile t+1 staged at t.P0 (h0:
// 4 loads) and t.P1 (h1: 4 loads); overwrite of buf cur happens >=2
// barriers after its last ds_read's lgkmcnt(0).
template<int N, int K, int LOGNB, int OUT_BF16, int RELU>
__global__ __launch_bounds__(512, 2)
void gemm_8p(const u16* __restrict__ A, const u16* __restrict__ Bw,
             const float* __restrict__ bias, void* __restrict__ Cout)
{
  __shared__ __align__(16) u16 As[2][16384];   // 2 x 32 KB (2 slabs x 256r x 4g x 16B)
  __shared__ __align__(16) u16 Bs[2][16384];   // 2 x 32 KB

  const int tid  = threadIdx.x;
  const int lane = tid & 63;
  const int wave = tid >> 6;
  const int bid  = blockIdx.x;
  const int xcd  = bid & 7;
  const int s    = bid >> 3;
  const int m0 = (xcd * 16 + (s >> LOGNB)) * 256;
  const int n0 = (s & ((1 << LOGNB) - 1)) * 256;
  const int wmr = (wave >> 2) * 128;   // wave m-origin (2 m-waves x 128)
  const int wn  = (wave & 3) * 64;     // wave n-origin (4 n-waves x 64)

  f32x4 acc[8][4];
#pragma unroll
  for (int i = 0; i < 8; ++i)
#pragma unroll
    for (int j = 0; j < 4; ++j) acc[i][j] = f32x4{0.f, 0.f, 0.f, 0.f};

  // staging source pointers: half h covers rows [128h,128h+128); thread's
  // row r = 128h + (tid>>2); swizzled octet koff = ((tid&3)^((tid>>3)&3))*8
  // (identical to validated R2 map per 32-k slab; (r>>1)&3 == (tid>>3)&3
  // for both halves since 128h and wave*16 are multiples of 4 after >>1).
  const int koff = (((tid & 3) ^ ((tid >> 3) & 3)) << 3);
  const u16* ApH[2]; const u16* BpH[2];
#pragma unroll
  for (int h = 0; h < 2; ++h) {
    int r = 128 * h + (tid >> 2);
    ApH[h] = A  + (size_t)(m0 + r) * K + koff;
    BpH[h] = Bw + (size_t)(n0 + r) * K + koff;
  }
  const int ldsWave = wave * 64;   // per-wave granule base within an issue

  // fragment granule offsets (validated map, per slab kk):
  // slot = kk*1024 + m*4 + (q ^ ((m>>1)&3)); u16 offset = slot*8
  const int fm = lane & 15;
  const int q  = lane >> 4;
  int aoffs[4][2], boffs[4][2];
#pragma unroll
  for (int i = 0; i < 4; ++i) {
    int m = wmr + i * 16 + fm;           // mh=0 rows; mh=1 adds 64 rows (+2048 u16)
    int n = wn  + i * 16 + fm;
#pragma unroll
    for (int kk = 0; kk < 2; ++kk) {
      aoffs[i][kk] = (kk * 1024 + m * 4 + (q ^ ((m >> 1) & 3))) * 8;
      boffs[i][kk] = (kk * 1024 + n * 4 + (q ^ ((n >> 1) & 3))) * 8;
    }
  }

  bf16x8 aH[4][2];   // current m-half A fragments (overwritten P0/P2)
  bf16x8 bF[4][2];   // all 4 n-frags, both slabs (filled P0/P1, live to P3)

  auto stageA = [&](int buf, int kt, int h) {
#pragma unroll
    for (int kk = 0; kk < 2; ++kk)
      __builtin_amdgcn_global_load_lds(GLB_AS(ApH[h] + kt + kk * 32),
          LDS_AS(&As[buf][(kk * 1024 + 512 * h + ldsWave) * 8]), 16, 0, 0);
  };
  auto stageB = [&](int buf, int kt, int h) {
#pragma unroll
    for (int kk = 0; kk < 2; ++kk)
      __builtin_amdgcn_global_load_lds(GLB_AS(BpH[h] + kt + kk * 32),
          LDS_AS(&Bs[buf][(kk * 1024 + 512 * h + ldsWave) * 8]), 16, 0, 0);
  };
  auto readA = [&](int buf, int mh) {
#pragma unroll
    for (int mf = 0; mf < 4; ++mf)
#pragma unroll
      for (int kk = 0; kk < 2; ++kk)
        aH[mf][kk] = *(const bf16x8*)&As[buf][aoffs[mf][kk] + mh * 2048];
  };
  auto readB = [&](int buf, int nh) {
#pragma unroll
    for (int nf = 0; nf < 2; ++nf)
#pragma unroll
      for (int kk = 0; kk < 2; ++kk)
        bF[nh * 2 + nf][kk] = *(const bf16x8*)&Bs[buf][boffs[nh * 2 + nf][kk]];
  };
  auto mfmaQ = [&](int mh, int nh) {
#pragma unroll
    for (int mf = 0; mf < 4; ++mf)
#pragma unroll
      for (int nf = 0; nf < 2; ++nf)
#pragma unroll
        for (int kk = 0; kk < 2; ++kk)
          acc[mh * 4 + mf][nh * 2 + nf] =
            __builtin_amdgcn_mfma_f32_16x16x32_bf16(aH[mf][kk], bF[nh * 2 + nf][kk],
                                                    acc[mh * 4 + mf][nh * 2 + nf], 0, 0, 0);
  };

  constexpr int NT = K / 64;
  // prologue: tile 0 fully staged into buf 0 (8 loads)
  stageA(0, 0, 0); stageA(0, 0, 1); stageB(0, 0, 0); stageB(0, 0, 1);
  int cur = 0;
  for (int t = 0; t < NT; ++t) {
    const int nxt = cur ^ 1;
    const bool pre = (t + 1 < NT);
    const int ktn = (t + 1) * 64;
    // ---- P0 ----
    if (pre) { stageA(nxt, ktn, 0); stageB(nxt, ktn, 0); }   // 4 loads (t+1, h0)
    if (pre) asm volatile("s_waitcnt vmcnt(4)" ::: "memory");
    else     asm volatile("s_waitcnt vmcnt(0)" ::: "memory");
    __builtin_amdgcn_s_barrier();         // all waves: tile t fully in LDS
    readA(cur, 0); readB(cur, 0);         // 12 x ds_read_b128
    asm volatile("s_waitcnt lgkmcnt(0)" ::: "memory");
    __builtin_amdgcn_sched_barrier(0);
    __builtin_amdgcn_s_setprio(1); mfmaQ(0, 0); __builtin_amdgcn_s_setprio(0);
    __builtin_amdgcn_s_barrier();
    // ---- P1 ----
    if (pre) { stageA(nxt, ktn, 1); stageB(nxt, ktn, 1); }   // 4 loads (t+1, h1)
    readB(cur, 1);                        // 4 x ds_read_b128
    asm volatile("s_waitcnt lgkmcnt(0)" ::: "memory");
    __builtin_amdgcn_sched_barrier(0);
    __builtin_amdgcn_s_setprio(1); mfmaQ(0, 1); __builtin_amdgcn_s_setprio(0);
    __builtin_amdgcn_s_barrier();
    // ---- P2 ----
    readA(cur, 1);                        // 8 x ds_read_b128
    asm volatile("s_waitcnt lgkmcnt(0)" ::: "memory");
    __builtin_amdgcn_sched_barrier(0);
    __builtin_amdgcn_s_setprio(1); mfmaQ(1, 0); __builtin_amdgcn_s_setprio(0);
    __builtin_amdgcn_s_barrier();
    // ---- P3 ----
    __builtin_amdgcn_s_setprio(1); mfmaQ(1, 1); __builtin_amdgcn_s_setprio(0);
    __builtin_amdgcn_s_barrier();
    cur = nxt;
  }

  // epilogue: C/D layout col=lane&15, row=(lane>>4)*4+reg  (validated R1-R6)
  const int colL = lane & 15;
  const int rowQ = (lane >> 4) * 4;
#pragma unroll
  for (int mf = 0; mf < 8; ++mf) {
#pragma unroll
    for (int nf = 0; nf < 4; ++nf) {
      int col  = n0 + wn + nf * 16 + colL;
      int rowb = m0 + wmr + mf * 16 + rowQ;
      float bv = bias[col];
#pragma unroll
      for (int r = 0; r < 4; ++r) {
        float v = acc[mf][nf][r] + bv;
        if (RELU) v = fmaxf(v, 0.f);
        size_t idx = (size_t)(rowb + r) * N + col;
        if (OUT_BF16) ((u16*)Cout)[idx] = f2bf(v);
        else          ((float*)Cout)[idx] = v;
      }
    }
  }
}

// ---------------- scan pass 1: per-chunk end state (R6-validated) ----------
__global__ __launch_bounds__(256)
void scan_chunk_end(const u16* __restrict__ u, const float* __restrict__ plog,
                    float2* __restrict__ e)
{
  const int t = threadIdx.x;          // channel pair 2t, 2t+1
  const int c = blockIdx.x;           // chunk 0..127 (32 steps each)
  const int b = blockIdx.y;
  float2 vl = ((const float2*)plog)[t];
  float2 tl = ((const float2*)plog)[256 + t];
  float v0 = expf(vl.x), v1 = expf(vl.y);
  float t0 = expf(tl.x), t1 = expf(tl.y);
  float m0 = expf(-v0), m1 = expf(-v1);
  float lr0 = m0 * cosf(t0), li0 = m0 * sinf(t0);
  float lr1 = m1 * cosf(t1), li1 = m1 * sinf(t1);
  const uint2* up = (const uint2*)u;            // 256 uint2 per row
  size_t idx = (size_t)(b * 4096 + c * 32) * 256 + t;
  float h0r = 0.f, h0i = 0.f, h1r = 0.f, h1i = 0.f;
#pragma unroll 8
  for (int s = 0; s < 32; ++s) {
    uint2 w = up[idx]; idx += 256;
    float u0r = bflo(w.x), u0i = bfhi(w.x);
    float u1r = bflo(w.y), u1i = bfhi(w.y);
    float n0r = fmaf(lr0, h0r, fmaf(-li0, h0i, u0r));
    float n0i = fmaf(lr0, h0i, fmaf( li0, h0r, u0i));
    float n1r = fmaf(lr1, h1r, fmaf(-li1, h1i, u1r));
    float n1i = fmaf(lr1, h1i, fmaf( li1, h1r, u1i));
    h0r = n0r; h0i = n0i; h1r = n1r; h1i = n1i;
  }
  ((float4*)e)[(size_t)(b * 128 + c) * 256 + t] = make_float4(h0r, h0i, h1r, h1i);
}

// ---------------- scan pass 1.5: in-place prefix (R6-validated) -------------
__global__ __launch_bounds__(256)
void scan_mid(const float* __restrict__ plog, float4* __restrict__ e)
{
  const int t = threadIdx.x;              // 0..255, channels 2t,2t+1
  const int b = blockIdx.x;               // batch 0..7
  float2 vl = ((const float2*)plog)[t];
  float2 tl = ((const float2*)plog)[256 + t];
  float v0 = expf(vl.x), v1 = expf(vl.y);
  float t0 = expf(tl.x), t1 = expf(tl.y);
  float Lm0 = expf(-32.f * v0), Lm1 = expf(-32.f * v1);
  float La0 = 32.f * t0,        La1 = 32.f * t1;
  float Lr0 = Lm0 * cosf(La0), Li0 = Lm0 * sinf(La0);
  float Lr1 = Lm1 * cosf(La1), Li1 = Lm1 * sinf(La1);
  float h0r = 0.f, h0i = 0.f, h1r = 0.f, h1i = 0.f;
  size_t base = (size_t)(b * 128) * 256 + t;    // float4 index, row stride 256
#pragma unroll 4
  for (int c = 0; c < 128; ++c) {
    float4 ec = e[base + (size_t)c * 256];
    float n0r = fmaf(Lr0, h0r, fmaf(-Li0, h0i, ec.x));
    float n0i = fmaf(Lr0, h0i, fmaf( Li0, h0r, ec.y));
    float n1r = fmaf(Lr1, h1r, fmaf(-Li1, h1i, ec.z));
    float n1i = fmaf(Lr1, h1i, fmaf( Li1, h1r, ec.w));
    h0r = n0r; h0i = n0i; h1r = n1r; h1i = n1i;
    e[base + (size_t)c * 256] = make_float4(h0r, h0i, h1r, h1i);
  }
}

// ---------------- scan pass 2 (carry lookup + output, R6-validated) ---------
__global__ __launch_bounds__(256)
void scan_out2(const u16* __restrict__ u, const float* __restrict__ plog,
               const float4* __restrict__ e, u16* __restrict__ xr)
{
  const int t = threadIdx.x;          // channel pair 2t, 2t+1
  const int c = blockIdx.x;
  const int b = blockIdx.y;
  float2 vl = ((const float2*)plog)[t];
  float2 tl = ((const float2*)plog)[256 + t];
  float2 gl = ((const float2*)plog)[512 + t];
  float v0 = expf(vl.x), v1 = expf(vl.y);
  float t0 = expf(tl.x), t1 = expf(tl.y);
  float g0 = expf(gl.x), g1 = expf(gl.y);
  float m0 = expf(-v0), m1 = expf(-v1);
  float lr0 = m0 * cosf(t0), li0 = m0 * sinf(t0);
  float lr1 = m1 * cosf(t1), li1 = m1 * sinf(t1);

  float h0r = 0.f, h0i = 0.f, h1r = 0.f, h1i = 0.f;
  if (c > 0) {
    float4 ec = e[(size_t)(b * 128 + c - 1) * 256 + t];
    h0r = ec.x; h0i = ec.y; h1r = ec.z; h1i = ec.w;
  }

  const uint2* up = (const uint2*)u;
  u32* xp = (u32*)xr;                 // 512 u32 per output row of 1024 u16
  size_t uidx = (size_t)(b * 4096 + c * 32) * 256 + t;
  size_t xidx = (size_t)(b * 4096 + c * 32) * 512 + t;
#pragma unroll 8
  for (int s = 0; s < 32; ++s) {
    uint2 w = up[uidx]; uidx += 256;
    float u0r = bflo(w.x), u0i = bfhi(w.x);
    float u1r = bflo(w.y), u1i = bfhi(w.y);
    float n0r = fmaf(lr0, h0r, fmaf(-li0, h0i, u0r));
    float n0i = fmaf(lr0, h0i, fmaf( li0, h0r, u0i));
    float n1r = fmaf(lr1, h1r, fmaf(-li1, h1i, u1r));
    float n1i = fmaf(lr1, h1i, fmaf( li1, h1r, u1i));
    h0r = n0r; h0i = n0i; h1r = n1r; h1i = n1i;
    xp[xidx]       = (u32)f2bf(g0 * h0r) | ((u32)f2bf(g1 * h1r) << 16);
    xp[xidx + 256] = (u32)f2bf(g0 * h0i) | ((u32)f2bf(g1 * h1i) << 16);
    xidx += 512;
  }
}

// ---------------- launch ----------------
extern "C" void kernel_launch(void* const* d_in, const int* in_sizes, int n_in,
                              void* d_out, int out_size, void* d_ws, size_t ws_size,
                              hipStream_t stream)
{
  (void)in_sizes; (void)n_in; (void)out_size; (void)ws_size;
  const float* inputs = (const float*)d_in[0];
  const float* Wi     = (const float*)d_in[1];
  const float* bi     = (const float*)d_in[2];
  const float* Wo     = (const float*)d_in[3];
  const float* bo     = (const float*)d_in[4];
  const float* plog   = (const float*)d_in[5];

  char* ws = (char*)d_ws;
  u16*    xrA   = (u16*)(ws);                        // A_bf then xr_bf (64 MB)
  u16*    u_bf  = (u16*)(ws + 67108864ull);          // 64 MB
  u16*    Wi_bf = (u16*)(ws + 134217728ull);         // 1 MB
  u16*    Wo_bf = (u16*)(ws + 135266304ull);         // 1 MB
  float2* e_b   = (float2*)(ws + 136314880ull);      // 4 MB (8 x 128 x 512 float2)

  // 1) convert all three fp32 tensors to bf16 (one launch)
  conv3_f32_bf16<<<17408, 256, 0, stream>>>(inputs, xrA, Wi, Wi_bf, Wo, Wo_bf);

  // 2) u = X @ Wi^T + bi   (M=32768, N=1024, K=512), bf16 out
  //    128 m-tiles (16/XCD) x 4 n-tiles = 512 blocks of 256x256, 8-phase
  gemm_8p<1024, 512, 2, 1, 0><<<512, 512, 0, stream>>>(xrA, Wi_bf, bi, u_bf);

  // 3) chunked complex prefix scan + gamma, write xr (bf16) over A region
  scan_chunk_end<<<dim3(128, 8), 256, 0, stream>>>(u_bf, plog, e_b);
  scan_mid<<<8, 256, 0, stream>>>(plog, (float4*)e_b);
  scan_out2<<<dim3(128, 8), 256, 0, stream>>>(u_bf, plog, (const float4*)e_b, xrA);

  // 4) out = relu(xr @ Wo^T + bo)  (M=32768, N=512, K=1024), fp32 out
  //    128 m-tiles (16/XCD) x 2 n-tiles = 256 blocks of 256x256, 8-phase
  gemm_8p<512, 1024, 1, 0, 1><<<256, 512, 0, stream>>>(xrA, Wo_bf, bo, d_out);
}